// Round 17
// baseline (392.310 us; speedup 1.0000x reference)
//
#include <hip/hip_runtime.h>
#include <hip/hip_bf16.h>
#include <hip/hip_fp16.h>
#include <stdint.h>

#define B_  32
#define E_  512
#define WN  2048
#define D_  1024

typedef __attribute__((ext_vector_type(8))) short short8;
typedef __attribute__((ext_vector_type(8))) _Float16 half8;
typedef __attribute__((ext_vector_type(4))) float f32x4;

__device__ int g_mask_is_int;   // 1 if mask buffer is int32 per element, 0 if uint8

__device__ __forceinline__ unsigned short f2bf(float f) {
  unsigned int u = __float_as_uint(f);
  u += 0x7fffu + ((u >> 16) & 1u);   // round-to-nearest-even
  return (unsigned short)(u >> 16);
}
__device__ __forceinline__ float bf2f(unsigned short s) {
  return __uint_as_float(((unsigned int)s) << 16);
}
__device__ __forceinline__ unsigned short f2h(float f) {
  return __half_as_ushort(__float2half(f));   // RTNE f32->f16
}
__device__ __forceinline__ float ftanh(float x) {
  float e = __expf(2.0f * x);
  return 1.0f - 2.0f / (e + 1.0f);
}
// XOR-swizzled byte offset within a [rows][128B] LDS plane
__device__ __forceinline__ int swz(int row, int kb) {
  return row * 128 + (kb ^ ((row & 7) << 4));
}
// 64B-row swizzle: F(X) = X ^ ((X>>6 & 7) << 4)
__device__ __forceinline__ int swz64x(int row, int kb) {
  const int X = row * 64 + kb;
  return X ^ (((X >> 6) & 7) << 4);
}
__device__ __forceinline__ uint4 pack8(unsigned short a0, unsigned short a1,
                                       unsigned short a2, unsigned short a3,
                                       unsigned short a4, unsigned short a5,
                                       unsigned short a6, unsigned short a7) {
  uint4 v;
  v.x = (unsigned int)a0 | ((unsigned int)a1 << 16);
  v.y = (unsigned int)a2 | ((unsigned int)a3 << 16);
  v.z = (unsigned int)a4 | ((unsigned int)a5 << 16);
  v.w = (unsigned int)a6 | ((unsigned int)a7 << 16);
  return v;
}
// async global->LDS, 16B per lane; LDS dst is wave-uniform base (+lane*16 HW)
__device__ __forceinline__ void gload_lds16(const void* g, void* l) {
  __builtin_amdgcn_global_load_lds(
      (const __attribute__((address_space(1))) unsigned int*)g,
      (__attribute__((address_space(3))) unsigned int*)l, 16, 0, 0);
}

// ---------------------------------------------------------------------------
// K0: detect mask dtype. int32 0/1 data => bytes at offset %4 != 0 are all 0.
// ---------------------------------------------------------------------------
__global__ void k_detect(const unsigned char* __restrict__ m) {
  if (threadIdx.x == 0) {
    int nz = 0;
    for (int i = 0; i < 1024; ++i)
      if ((i & 3) && m[i]) nz++;
    g_mask_is_int = (nz == 0) ? 1 : 0;
  }
}

// ===========================================================================
// FAST PATH
// ===========================================================================

// ---------------------------------------------------------------------------
// k_proj_fused: proj = tanh(ems @ W^T + bias), single f16 MFMA. ems/W are
// reg-staged f32->f16 (split kernels eliminated). 64KB LDS dbuf, 1 barrier
// per stage (pv-verified pattern), XCD-pinned. Epilogue: f16 plane blob
// (verified r15).
// ---------------------------------------------------------------------------
__global__ __launch_bounds__(512) void k_proj_fused(
    const float* __restrict__ ems, const float* __restrict__ W,
    const float* __restrict__ bias, unsigned short* __restrict__ outF) {
  __shared__ uint4 lds4[4096];   // 64KB
  char* pA_c = (char*)lds4;
  char* pB_c = (char*)lds4 + 16384;
  char* pA_n = (char*)lds4 + 32768;
  char* pB_n = (char*)lds4 + 49152;

  const int g = blockIdx.x;
  const int xcd = g & 7;
  const int slot = g >> 3;               // 0..127
  const int Tm = xcd + 8 * (slot >> 3);  // 0..127, pinned to XCD
  const int Tn = slot & 7;               // 0..7
  const int t = threadIdx.x, l = t & 63, wv = t >> 6;
  const int wm2 = wv >> 1;   // 0..3 -> rows wm2*32
  const int wn2 = wv & 1;    // 0..1 -> cols wn2*64

  const int srow = t >> 2;        // staging row 0..127
  const int sc16 = (t & 3) * 16;  // f32 col base

  f32x4 acc[2][4];
#pragma unroll
  for (int i = 0; i < 2; ++i)
#pragma unroll
    for (int j = 0; j < 4; ++j) acc[i][j] = (f32x4){0.f, 0.f, 0.f, 0.f};

  f32x4 ar[4], br[4];

  auto load_stage = [&](int s) {
    const float* ap = ems + ((size_t)(Tm * 128 + srow)) * 1024 + s * 64 + sc16;
    const float* bp = W + ((size_t)(Tn * 128 + srow)) * 1024 + s * 64 + sc16;
#pragma unroll
    for (int i = 0; i < 4; ++i) {
      ar[i] = *(const f32x4*)(ap + i * 4);
      br[i] = *(const f32x4*)(bp + i * 4);
    }
  };

  auto write_stage = [&](char* pA, char* pB) {
    unsigned short ha[16], hb[16];
#pragma unroll
    for (int i = 0; i < 4; ++i)
#pragma unroll
      for (int j2 = 0; j2 < 4; ++j2) {
        ha[i * 4 + j2] = f2h(ar[i][j2]);
        hb[i * 4 + j2] = f2h(br[i][j2]);
      }
    const int o0 = swz(srow, sc16 * 2);
    const int o1 = swz(srow, sc16 * 2 + 16);
    *(uint4*)(pA + o0) = pack8(ha[0], ha[1], ha[2], ha[3], ha[4], ha[5], ha[6], ha[7]);
    *(uint4*)(pA + o1) = pack8(ha[8], ha[9], ha[10], ha[11], ha[12], ha[13], ha[14], ha[15]);
    *(uint4*)(pB + o0) = pack8(hb[0], hb[1], hb[2], hb[3], hb[4], hb[5], hb[6], hb[7]);
    *(uint4*)(pB + o1) = pack8(hb[8], hb[9], hb[10], hb[11], hb[12], hb[13], hb[14], hb[15]);
  };

  auto compute_stage = [&](const char* pA, const char* pB) {
#pragma unroll
    for (int ks = 0; ks < 2; ++ks) {
      const int kb = ks * 64 + (l >> 4) * 16;
      half8 a[2], bf[4];
#pragma unroll
      for (int f = 0; f < 2; ++f)
        a[f] = *(const half8*)(pA + swz(wm2 * 32 + f * 16 + (l & 15), kb));
#pragma unroll
      for (int f = 0; f < 4; ++f)
        bf[f] = *(const half8*)(pB + swz(wn2 * 64 + f * 16 + (l & 15), kb));
#pragma unroll
      for (int fm = 0; fm < 2; ++fm)
#pragma unroll
        for (int fn = 0; fn < 4; ++fn)
          acc[fm][fn] = __builtin_amdgcn_mfma_f32_16x16x32_f16(a[fm], bf[fn], acc[fm][fn], 0, 0, 0);
    }
  };

  load_stage(0);
  write_stage(pA_c, pB_c);
  __syncthreads();
  for (int s = 0; s < 16; ++s) {
    if (s < 15) load_stage(s + 1);
    compute_stage(pA_c, pB_c);
    if (s < 15) write_stage(pA_n, pB_n);
    __syncthreads();
    char* x;
    x = pA_c; pA_c = pA_n; pA_n = x;
    x = pB_c; pB_c = pB_n; pB_n = x;
  }

  float bcol[4];
#pragma unroll
  for (int fn = 0; fn < 4; ++fn)
    bcol[fn] = bias[Tn * 128 + wn2 * 64 + fn * 16 + (l & 15)];
#pragma unroll
  for (int fm = 0; fm < 2; ++fm)
#pragma unroll
    for (int fn = 0; fn < 4; ++fn)
#pragma unroll
      for (int q = 0; q < 4; ++q)
        acc[fm][fn][q] = ftanh(acc[fm][fn][q] + bcol[fn]);

  // epilogue: LDS transpose (f16 bits) then 32-k-stage blob store (one plane)
  unsigned short* ldsT = (unsigned short*)lds4;  // [128][136] = 34KB < 64KB
  __syncthreads();
#pragma unroll
  for (int fm = 0; fm < 2; ++fm)
#pragma unroll
    for (int fn = 0; fn < 4; ++fn)
#pragma unroll
      for (int q = 0; q < 4; ++q) {
        const int rl = wm2 * 32 + fm * 16 + (l >> 4) * 4 + q;
        const int cl = wn2 * 64 + fn * 16 + (l & 15);
        ldsT[rl * 136 + cl] = f2h(acc[fm][fn][q]);
      }
  __syncthreads();
#pragma unroll
  for (int sb = 0; sb < 4; ++sb) {
    const int L = t * 16;
    const int x6 = ((L >> 6) ^ (L >> 8)) & 1;
    const int x5 = ((L >> 5) ^ (L >> 7)) & 1;
    const int x4 = ((L >> 4) ^ (L >> 6) ^ (L >> 8)) & 1;
    const int X = (L & ~0x70) | (x6 << 6) | (x5 << 5) | (x4 << 4);
    const int row = X >> 6;
    const int cl = sb * 32 + ((X & 63) >> 1);
    uint4 v = *(const uint4*)(ldsT + row * 136 + cl);
    *(uint4*)((char*)outF + (size_t)Tm * 262144 +
              (size_t)(Tn * 4 + sb) * 8192 + L) = v;
  }
}

// ---------------------------------------------------------------------------
// k_scores_mfma: single f16 MFMA, f16 score store (verified rounds 14-16).
// ---------------------------------------------------------------------------
__global__ __launch_bounds__(512) void k_scores_mfma(
    const unsigned short* __restrict__ pF,
    const float* __restrict__ words, unsigned short* __restrict__ sc) {
  __shared__ uint4 lds4[5120];  // 80KB
  char* pA_c = (char*)lds4;              // 32KB: [4 tiles][8KB swz64x]
  char* pA_n = (char*)lds4 + 32768;
  char* pB_c = (char*)lds4 + 65536;      // 8KB: [128 n][64B swz64x]
  char* pB_n = (char*)lds4 + 73728;

  const int g = blockIdx.x;
  const int b = (g & 7) + 8 * (g >> 7);   // XCD-pinned batch (bijective)
  const int n0 = ((g >> 3) & 15) * 128;

  const int t = threadIdx.x, l = t & 63, wv = t >> 6;
  const int wm4 = wv >> 1;    // 0..3 -> m tile (128 rows each)
  const int wn2 = wv & 1;     // 0..1 -> n base local = wn2*64

  f32x4 acc[8][4];
#pragma unroll
  for (int i = 0; i < 8; ++i)
#pragma unroll
    for (int j = 0; j < 4; ++j) acc[i][j] = (f32x4){0.f, 0.f, 0.f, 0.f};

  f32x4 br0, br1;
  const int bn = t >> 2;          // B n-row 0..127
  const int bc = (t & 3) * 8;     // f32 col base within 32

  auto dma_A = [&](int s, char* pA) {
#pragma unroll
    for (int j = 0; j < 4; ++j) {
      const size_t gb = (size_t)(b * 4 + j) * 262144 + (size_t)s * 8192 +
                        wv * 1024 + l * 16;
      gload_lds16((const char*)pF + gb, pA + j * 8192 + wv * 1024);
    }
  };

  auto load_B = [&](int s) {
    const float* bs = words + (size_t)b * WN * D_ + (size_t)(n0 + bn) * 1024 +
                      s * 32 + bc;
    br0 = *(const f32x4*)(bs);
    br1 = *(const f32x4*)(bs + 4);
  };

  auto write_B = [&](char* pB) {
    unsigned short hB[8];
#pragma unroll
    for (int j = 0; j < 4; ++j) {
      hB[j] = f2h(br0[j]);
      hB[4 + j] = f2h(br1[j]);
    }
    const int o = swz64x(bn, (t & 3) * 16);
    *(uint4*)(pB + o) = pack8(hB[0], hB[1], hB[2], hB[3], hB[4], hB[5], hB[6], hB[7]);
  };

  auto compute_stage = [&](const char* pA, const char* pB) {
    const int kb0 = (l >> 4) * 16;
    half8 bf[4];
#pragma unroll
    for (int f = 0; f < 4; ++f) {
      const int n = wn2 * 64 + f * 16 + (l & 15);
      bf[f] = *(const half8*)(pB + swz64x(n, kb0));
    }
#pragma unroll
    for (int fm = 0; fm < 8; ++fm) {
      const int row = fm * 16 + (l & 15);
      const half8 a = *(const half8*)(pA + wm4 * 8192 + swz64x(row, kb0));
#pragma unroll
      for (int fn = 0; fn < 4; ++fn)
        acc[fm][fn] = __builtin_amdgcn_mfma_f32_16x16x32_f16(a, bf[fn], acc[fm][fn], 0, 0, 0);
    }
  };

  // prologue
  load_B(0);
  dma_A(0, pA_c);
  write_B(pB_c);
  __syncthreads();

  for (int s = 0; s < 32; ++s) {
    if (s < 31) {
      load_B(s + 1);
      dma_A(s + 1, pA_n);
    }
    compute_stage(pA_c, pB_c);
    if (s < 31) write_B(pB_n);
    __syncthreads();  // drains DMA (vmcnt) + ds_writes (lgkm)
    char* x;
    x = pA_c; pA_c = pA_n; pA_n = x;
    x = pB_c; pB_c = pB_n; pB_n = x;
  }

  // store f16 scores
#pragma unroll
  for (int fm = 0; fm < 8; ++fm)
#pragma unroll
    for (int fn = 0; fn < 4; ++fn)
#pragma unroll
      for (int q = 0; q < 4; ++q) {
        const int row = wm4 * 128 + fm * 16 + (l >> 4) * 4 + q;
        const int col = n0 + wn2 * 64 + fn * 16 + (l & 15);
        sc[((size_t)b * 512 + row) * 2048 + col] = f2h(acc[fm][fn][q]);
      }
}

// ---------------------------------------------------------------------------
// k_softmax: reads f16 scores, writes f16 att blob in 32-n-stage swz64x
// layout (matches new k_pv): dst stage = t>>2, offset swz64x(ee,(t&3)*16).
// ---------------------------------------------------------------------------
__global__ __launch_bounds__(256) void k_softmax(const unsigned short* __restrict__ sc,
                                                 const void* __restrict__ mask,
                                                 unsigned short* __restrict__ blob) {
  __shared__ float red[8];
  const int row = blockIdx.x;
  const int t = threadIdx.x;
  const int wave = t >> 6;
  const unsigned short* rp = sc + (size_t)row * 2048;
  float v[8];
  {
    const half8 hv = *(const half8*)(rp + t * 8);
#pragma unroll
    for (int i = 0; i < 8; ++i) v[i] = (float)hv[i];
  }
  if (g_mask_is_int) {
    const int* mp = (const int*)mask + (size_t)row * 2048 + t * 8;
    const int4 m0 = *(const int4*)mp;
    const int4 m1 = *(const int4*)(mp + 4);
    if (m0.x) v[0] = -INFINITY;
    if (m0.y) v[1] = -INFINITY;
    if (m0.z) v[2] = -INFINITY;
    if (m0.w) v[3] = -INFINITY;
    if (m1.x) v[4] = -INFINITY;
    if (m1.y) v[5] = -INFINITY;
    if (m1.z) v[6] = -INFINITY;
    if (m1.w) v[7] = -INFINITY;
  } else {
    const unsigned char* mp = (const unsigned char*)mask + (size_t)row * 2048 + t * 8;
    const uchar4 m0 = *(const uchar4*)mp;
    const uchar4 m1 = *(const uchar4*)(mp + 4);
    if (m0.x) v[0] = -INFINITY;
    if (m0.y) v[1] = -INFINITY;
    if (m0.z) v[2] = -INFINITY;
    if (m0.w) v[3] = -INFINITY;
    if (m1.x) v[4] = -INFINITY;
    if (m1.y) v[5] = -INFINITY;
    if (m1.z) v[6] = -INFINITY;
    if (m1.w) v[7] = -INFINITY;
  }
  float mx = v[0];
#pragma unroll
  for (int i = 1; i < 8; ++i) mx = fmaxf(mx, v[i]);
#pragma unroll
  for (int off = 32; off > 0; off >>= 1) mx = fmaxf(mx, __shfl_xor(mx, off));
  if ((t & 63) == 0) red[wave] = mx;
  __syncthreads();
  mx = fmaxf(fmaxf(red[0], red[1]), fmaxf(red[2], red[3]));
  float e[8];
  float sum = 0.0f;
#pragma unroll
  for (int i = 0; i < 8; ++i) {
    e[i] = __expf(v[i] - mx);
    sum += e[i];
  }
#pragma unroll
  for (int off = 32; off > 0; off >>= 1) sum += __shfl_xor(sum, off);
  if ((t & 63) == 0) red[4 + wave] = sum;
  __syncthreads();
  const float tot = (red[4] + red[5]) + (red[6] + red[7]);
  const float rinv = 1.0f / tot;

  const int b = row >> 9, ee = row & 511;
  const uint4 pk = pack8(f2h(e[0] * rinv), f2h(e[1] * rinv),
                         f2h(e[2] * rinv), f2h(e[3] * rinv),
                         f2h(e[4] * rinv), f2h(e[5] * rinv),
                         f2h(e[6] * rinv), f2h(e[7] * rinv));
  char* dst = (char*)blob + (size_t)b * 2097152 + (size_t)(t >> 2) * 32768 +
              swz64x(ee, (t & 3) * 16);
  *(uint4*)dst = pk;
}

// ---------------------------------------------------------------------------
// k_pv v3: ctx = att @ words, f16 MFMA. Scores-verified skeleton: BM=256 x
// BW=128, BK=32, 48KB LDS dbuf -> 2 blocks/CU (acc[4][4] keeps VGPR<128).
// A via DMA from 32-n-stage swz64x att blob; B reg-staged f16.
// Grid 512 = 32b x 8wt x 2m, XCD-pinned by b.
// ---------------------------------------------------------------------------
__global__ __launch_bounds__(512) void k_pv(
    const unsigned short* __restrict__ blob, const float* __restrict__ words,
    float* __restrict__ ctx) {
  __shared__ uint4 lds4[3072];   // 48KB: A_c 16K | A_n 16K | B_c 8K | B_n 8K
  char* pA_c = (char*)lds4;
  char* pA_n = (char*)lds4 + 16384;
  char* pB_c = (char*)lds4 + 32768;
  char* pB_n = (char*)lds4 + 40960;

  const int g = blockIdx.x;
  const int xcd = g & 7;
  const int slot = g >> 3;            // 0..63
  const int b = xcd + 8 * (slot >> 4);
  const int inner = slot & 15;
  const int wt = inner & 7;
  const int m0 = (inner >> 3) * 256;  // 0 or 256
  const int w0 = wt * 128;

  const int t = threadIdx.x, l = t & 63, wv = t >> 6;
  const int wm4 = wv >> 1;    // 0..3 -> rows m-local wm4*64
  const int wn2 = wv & 1;     // 0..1 -> cols w-local wn2*64

  const char* blobB = (const char*)blob + (size_t)b * 2097152;

  f32x4 acc[4][4];
#pragma unroll
  for (int i = 0; i < 4; ++i)
#pragma unroll
    for (int j = 0; j < 4; ++j) acc[i][j] = (f32x4){0.f, 0.f, 0.f, 0.f};

  f32x4 br0, br1;
  const int np = (t & 15) * 2;    // n-local pair base 0..30
  const int wc = (t >> 4) * 4;    // w chunk 0..124

  auto dma_A = [&](int s, char* pA) {
    const char* gp = blobB + (size_t)s * 32768 + m0 * 64 + wv * 2048 + l * 16;
#pragma unroll
    for (int j = 0; j < 2; ++j)
      gload_lds16(gp + j * 1024, pA + wv * 2048 + j * 1024);
  };

  auto load_B = [&](int s) {
    const float* wp = words + (size_t)b * WN * D_ +
                      (size_t)(s * 32 + np) * 1024 + w0 + wc;
    br0 = *(const f32x4*)(wp);
    br1 = *(const f32x4*)(wp + 1024);
  };

  auto write_B = [&](char* pB) {
#pragma unroll
    for (int i = 0; i < 4; ++i) {
      const int w = wc + i;
      const unsigned int pk =
          (unsigned int)f2h(br0[i]) | ((unsigned int)f2h(br1[i]) << 16);
      *(unsigned int*)(pB + swz64x(w, np * 2)) = pk;
    }
  };

  auto compute_stage = [&](const char* pA, const char* pB) {
    const int kb0 = (l >> 4) * 16;
    half8 bb[4];
#pragma unroll
    for (int f = 0; f < 4; ++f) {
      const int row = wn2 * 64 + f * 16 + (l & 15);
      bb[f] = *(const half8*)(pB + swz64x(row, kb0));
    }
#pragma unroll
    for (int fm = 0; fm < 4; ++fm) {
      const int row = wm4 * 64 + fm * 16 + (l & 15);
      const half8 a = *(const half8*)(pA + swz64x(row, kb0));
#pragma unroll
      for (int fn = 0; fn < 4; ++fn)
        acc[fm][fn] = __builtin_amdgcn_mfma_f32_16x16x32_f16(a, bb[fn], acc[fm][fn], 0, 0, 0);
    }
  };

  load_B(0);
  dma_A(0, pA_c);
  write_B(pB_c);
  __syncthreads();

  for (int s = 0; s < 64; ++s) {
    if (s < 63) {
      load_B(s + 1);
      dma_A(s + 1, pA_n);
    }
    compute_stage(pA_c, pB_c);
    if (s < 63) write_B(pB_n);
    __syncthreads();  // drains DMA (vmcnt) + ds_writes (lgkm)
    char* x;
    x = pA_c; pA_c = pA_n; pA_n = x;
    x = pB_c; pB_c = pB_n; pB_n = x;
  }

#pragma unroll
  for (int fm = 0; fm < 4; ++fm)
#pragma unroll
    for (int fn = 0; fn < 4; ++fn)
#pragma unroll
      for (int q = 0; q < 4; ++q) {
        const int row = m0 + wm4 * 64 + fm * 16 + (l >> 4) * 4 + q;
        const int col = w0 + wn2 * 64 + fn * 16 + (l & 15);
        ctx[((size_t)b * 512 + row) * 1024 + col] = acc[fm][fn][q];
      }
}

// ---------------------------------------------------------------------------
// k_copy: ctx (ws) -> d_out, float4 grid-stride. (small-ws fallback only)
// ---------------------------------------------------------------------------
__global__ __launch_bounds__(256) void k_copy(const float4* __restrict__ src,
                                              float4* __restrict__ dst) {
  const int n4 = 16384 * 1024 / 4;
  int i = blockIdx.x * 256 + threadIdx.x;
  const int stride = gridDim.x * 256;
  for (; i < n4; i += stride) dst[i] = src[i];
}

// ===========================================================================
// FALLBACK PATH (round-2 verified kernels; used if ws too small)
// ===========================================================================
__global__ __launch_bounds__(256, 4) void k_proj(const float* __restrict__ A,
                                                 const float* __restrict__ W,
                                                 const float* __restrict__ bias,
                                                 float* __restrict__ out) {
  __shared__ float As[32][132];
  __shared__ float Bs[32][132];
  const int t = threadIdx.x;
  const int m0 = blockIdx.x * 128;
  const int n0 = blockIdx.y * 128;
  const int tm = t >> 4;
  const int tn = t & 15;
  const int lrow = t >> 1;
  const int lk = (t & 1) * 16;

  float acc[8][8];
#pragma unroll
  for (int i = 0; i < 8; ++i)
#pragma unroll
    for (int j = 0; j < 8; ++j) acc[i][j] = 0.0f;

  const float* Arow = A + (size_t)(m0 + lrow) * D_ + lk;
  const float* Wrow = W + (size_t)(n0 + lrow) * D_ + lk;

  for (int k0 = 0; k0 < D_; k0 += 32) {
    __syncthreads();
#pragma unroll
    for (int j = 0; j < 4; ++j) {
      const float4 va = *(const float4*)(Arow + k0 + j * 4);
      As[lk + j * 4 + 0][lrow] = va.x;
      As[lk + j * 4 + 1][lrow] = va.y;
      As[lk + j * 4 + 2][lrow] = va.z;
      As[lk + j * 4 + 3][lrow] = va.w;
      const float4 vb = *(const float4*)(Wrow + k0 + j * 4);
      Bs[lk + j * 4 + 0][lrow] = vb.x;
      Bs[lk + j * 4 + 1][lrow] = vb.y;
      Bs[lk + j * 4 + 2][lrow] = vb.z;
      Bs[lk + j * 4 + 3][lrow] = vb.w;
    }
    __syncthreads();
#pragma unroll 8
    for (int k = 0; k < 32; ++k) {
      float a[8], bb[8];
      *(float4*)(a + 0) = *(const float4*)&As[k][tm * 4];
      *(float4*)(a + 4) = *(const float4*)&As[k][tm * 4 + 64];
      *(float4*)(bb + 0) = *(const float4*)&Bs[k][tn * 4];
      *(float4*)(bb + 4) = *(const float4*)&Bs[k][tn * 4 + 64];
#pragma unroll
      for (int i = 0; i < 8; ++i)
#pragma unroll
        for (int j = 0; j < 8; ++j) acc[i][j] = fmaf(a[i], bb[j], acc[i][j]);
    }
  }

  float bn[8];
#pragma unroll
  for (int j = 0; j < 8; ++j) bn[j] = bias[n0 + tn * 4 + (j & 3) + (j >> 2) * 64];
#pragma unroll
  for (int i = 0; i < 8; ++i) {
    const int m = m0 + tm * 4 + (i & 3) + (i >> 2) * 64;
    float4 v0, v1;
    v0.x = tanhf(acc[i][0] + bn[0]);
    v0.y = tanhf(acc[i][1] + bn[1]);
    v0.z = tanhf(acc[i][2] + bn[2]);
    v0.w = tanhf(acc[i][3] + bn[3]);
    v1.x = tanhf(acc[i][4] + bn[4]);
    v1.y = tanhf(acc[i][5] + bn[5]);
    v1.z = tanhf(acc[i][6] + bn[6]);
    v1.w = tanhf(acc[i][7] + bn[7]);
    *(float4*)(out + (size_t)m * D_ + n0 + tn * 4) = v0;
    *(float4*)(out + (size_t)m * D_ + n0 + tn * 4 + 64) = v1;
  }
}

__global__ __launch_bounds__(256) void k_scores(const float* __restrict__ words,
                                                const void* __restrict__ mask,
                                                float* __restrict__ pa) {
  __shared__ float Pt[1024][18];
  __shared__ float Ws[64][268];
  const int t = threadIdx.x;
  const int b = blockIdx.x >> 5;
  const int et = blockIdx.x & 31;
  const int e0 = et * 16;
  const int eg = t >> 5;
  const int ng = t & 31;
  const int mask_is_int = g_mask_is_int;
  const float* wbase = words + (size_t)b * WN * D_;

  {
    const int row = t >> 4;
    const int dj = (t & 15) * 4;
    const float* pr = pa + (size_t)(b * E_ + e0 + row) * D_;
#pragma unroll
    for (int rr = 0; rr < 16; ++rr) {
      const float4 v = *(const float4*)(pr + dj + rr * 64);
      Pt[dj + rr * 64 + 0][row] = v.x;
      Pt[dj + rr * 64 + 1][row] = v.y;
      Pt[dj + rr * 64 + 2][row] = v.z;
      Pt[dj + rr * 64 + 3][row] = v.w;
    }
  }

  float s[2][64];
#pragma unroll
  for (int i = 0; i < 2; ++i)
#pragma unroll
    for (int u = 0; u < 64; ++u) s[i][u] = 0.0f;

  const int nl = t >> 3;
  const int d4 = (t & 7) * 4;

  for (int dk = 0; dk < D_; dk += 64) {
#pragma unroll
    for (int nb = 0; nb < 8; ++nb) {
      __syncthreads();
#pragma unroll
      for (int rr = 0; rr < 8; ++rr) {
#pragma unroll
        for (int hh = 0; hh < 2; ++hh) {
          const int n = nl + rr * 32;
          const int d = d4 + hh * 32;
          const float4 v = *(const float4*)(wbase + (size_t)(nb * 256 + n) * D_ + dk + d);
          Ws[d + 0][n] = v.x;
          Ws[d + 1][n] = v.y;
          Ws[d + 2][n] = v.z;
          Ws[d + 3][n] = v.w;
        }
      }
      __syncthreads();
#pragma unroll 2
      for (int k = 0; k < 64; ++k) {
        const float2 a = *(const float2*)&Pt[dk + k][eg * 2];
        const float4 b0 = *(const float4*)&Ws[k][ng * 4];
        const float4 b1 = *(const float4*)&Ws[k][128 + ng * 4];
        const float aa[2] = {a.x, a.y};
        const float bb[8] = {b0.x, b0.y, b0.z, b0.w, b1.x, b1.y, b1.z, b1.w};
#pragma unroll
        for (int i = 0; i < 2; ++i)
#pragma unroll
          for (int u = 0; u < 8; ++u)
            s[i][nb * 8 + u] = fmaf(aa[i], bb[u], s[i][nb * 8 + u]);
      }
    }
  }

#pragma unroll
  for (int i = 0; i < 2; ++i) {
    const int e = e0 + eg * 2 + i;
#pragma unroll
    for (int nb = 0; nb < 8; ++nb)
#pragma unroll
      for (int q = 0; q < 2; ++q) {
        const size_t moff = (size_t)(b * E_ + e) * WN + nb * 256 + q * 128 + ng * 4;
        int mx, my, mz, mw;
        if (mask_is_int) {
          const int4 mv = *(const int4*)((const int*)mask + moff);
          mx = mv.x; my = mv.y; mz = mv.z; mw = mv.w;
        } else {
          const uchar4 mv = *(const uchar4*)((const unsigned char*)mask + moff);
          mx = mv.x; my = mv.y; mz = mv.z; mw = mv.w;
        }
        if (mx) s[i][nb * 8 + q * 4 + 0] = -1e30f;
        if (my) s[i][nb * 8 + q * 4 + 1] = -1e30f;
        if (mz) s[i][nb * 8 + q * 4 + 2] = -1e30f;
        if (mw) s[i][nb * 8 + q * 4 + 3] = -1e30f;
      }
    float m = -1e30f;
#pragma unroll
    for (int u = 0; u < 64; ++u) m = fmaxf(m, s[i][u]);
#pragma unroll
    for (int off = 16; off > 0; off >>= 1) m = fmaxf(m, __shfl_xor(m, off));
    float sum = 0.0f;
#pragma unroll
    for (int u = 0; u < 64; ++u) {
      const float p = __expf(s[i][u] - m);
      s[i][u] = p;
      sum += p;
    }
#pragma unroll
    for (int off = 16; off > 0; off >>= 1) sum += __shfl_xor(sum, off);
    const float rinv = 1.0f / sum;

    unsigned short* ar2 = (unsigned short*)(pa + (size_t)(b * E_ + e) * WN / 2);
#pragma unroll
    for (int nb = 0; nb < 8; ++nb)
#pragma unroll
      for (int q = 0; q < 2; ++q) {
        ushort4 pk;
        pk.x = f2bf(s[i][nb * 8 + q * 4 + 0] * rinv);
        pk.y = f2bf(s[i][nb * 8 + q * 4 + 1] * rinv);
        pk.z = f2bf(s[i][nb * 8 + q * 4 + 2] * rinv);
        pk.w = f2bf(s[i][nb * 8 + q * 4 + 3] * rinv);
        *(ushort4*)(ar2 + nb * 256 + q * 128 + ng * 4) = pk;
      }
  }
}

__global__ __launch_bounds__(256) void k_ctx(const float* __restrict__ words,
                                             float* __restrict__ pa) {
  __shared__ unsigned short att_s[16][2048];
  __shared__ unsigned short Wb[256][132];
  const int t = threadIdx.x;
  const int b = blockIdx.x >> 5;
  const int et = blockIdx.x & 31;
  const int e0 = et * 16;
  const int eg = t >> 5;
  const int wg = t & 31;
  const float* wbase = words + (size_t)b * WN * D_;

  {
    const int row = t >> 4;
    const int cj = t & 15;
    const uint4* pr = (const uint4*)(pa + (size_t)(b * E_ + e0 + row) * D_);
#pragma unroll
    for (int rr = 0; rr < 16; ++rr) {
      const int c = cj + rr * 16;
      const uint4 v = pr[c];
      *(uint4*)&att_s[row][c * 8] = v;
    }
  }

  float acc[2][32];
#pragma unroll
  for (int i = 0; i < 2; ++i)
#pragma unroll
    for (int u = 0; u < 32; ++u) acc[i][u] = 0.0f;

  const int nlg = t >> 5;
  const int w4 = (t & 31) * 4;

  for (int nb = 0; nb < 8; ++nb) {
#pragma unroll
    for (int q = 0; q < 8; ++q) {
      __syncthreads();
#pragma unroll
      for (int rr = 0; rr < 32; ++rr) {
        const int n = nlg + rr * 8;
        const float4 v = *(const float4*)(wbase + (size_t)(nb * 256 + n) * D_ + q * 128 + w4);
        ushort4 pk;
        pk.x = f2bf(v.x);
        pk.y = f2bf(v.y);
        pk.z = f2bf(v.z);
        pk.w = f2bf(v.w);
        *(ushort4*)&Wb[n][w4] = pk;
      }
      __syncthreads();
#pragma unroll 4
      for (int n2 = 0; n2 < 128; ++n2) {
        const int n = n2 * 2;
        const ushort4 r0 = *(const ushort4*)&Wb[n][wg * 4];
        const ushort4 r1 = *(const ushort4*)&Wb[n + 1][wg * 4];
        const float w0[4] = {bf2f(r0.x), bf2f(r0.y), bf2f(r0.z), bf2f(r0.w)};
        const float w1[4] = {bf2f(r1.x), bf2f(r1.y), bf2f(r1.z), bf2f(r1.w)};
#pragma unroll
        for (int i = 0; i < 2; ++i) {
          const unsigned int aw = *(const unsigned int*)&att_s[eg * 2 + i][nb * 256 + n];
          const float a0 = bf2f((unsigned short)(aw & 0xffffu));
          const float a1 = bf2f((unsigned short)(aw >> 16));
#pragma unroll
          for (int j = 0; j < 4; ++j)
            acc[i][q * 4 + j] = fmaf(a0, w0[j], fmaf(a1, w1[j], acc[i][q * 4 + j]));
        }
      }
    }
  }

#pragma unroll
  for (int i = 0; i < 2; ++i) {
    float* orow = pa + (size_t)(b * E_ + e0 + eg * 2 + i) * D_;
#pragma unroll
    for (int q = 0; q < 8; ++q) {
      float4 v;
      v.x = acc[i][q * 4 + 0];
      v.y = acc[i][q * 4 + 1];
      v.z = acc[i][q * 4 + 2];
      v.w = acc[i][q * 4 + 3];
      *(float4*)(orow + q * 128 + wg * 4) = v;
    }
  }
}

extern "C" void kernel_launch(void* const* d_in, const int* in_sizes, int n_in,
                              void* d_out, int out_size, void* d_ws, size_t ws_size,
                              hipStream_t stream) {
  const float* ems = (const float*)d_in[0];
  const float* words = (const float*)d_in[1];
  const void* mask = d_in[2];
  const float* w_weight = (const float*)d_in[3];
  const float* w_bias = (const float*)d_in[4];

  k_detect<<<1, 64, 0, stream>>>((const unsigned char*)mask);

  const size_t ws_need = (size_t)16384 * 2048 * 4;          // 128 MB budget
  const size_t ws_big = ws_need + (size_t)32 * 2097152;     // +64 MB blob
  if (ws_size >= ws_need) {
    unsigned short* pF = (unsigned short*)d_out;    // 32MB f16 proj blob
    unsigned short* scH = (unsigned short*)d_ws;    // 64MB f16 scores
    // 1. proj (fused f32->f16 staging, single f16 MFMA, XCD-pinned)
    k_proj_fused<<<dim3(1024), 512, 0, stream>>>(ems, w_weight, w_bias, pF);
    // 2. scores (single f16 MFMA) -> f16 scores in ws[0..64MB)
    k_scores_mfma<<<dim3(512), 512, 0, stream>>>(pF, words, scH);
    if (ws_size >= ws_big) {
      // big-ws path: att blob in ws; ctx -> d_out direct
      unsigned short* blob = (unsigned short*)((char*)d_ws + ws_need);
      k_softmax<<<dim3(16384), 256, 0, stream>>>(scH, mask, blob);
      k_pv<<<dim3(512), 512, 0, stream>>>(blob, words, (float*)d_out);
    } else {
      // small-ws path: blob in d_out (proj blob dead), ctx -> ws+64MB, copy
      k_softmax<<<dim3(16384), 256, 0, stream>>>(scH, mask, (unsigned short*)d_out);
      k_pv<<<dim3(512), 512, 0, stream>>>((const unsigned short*)d_out, words,
                                          (float*)((char*)d_ws + 67108864));
      k_copy<<<dim3(2048), 256, 0, stream>>>(
          (const float4*)((char*)d_ws + 67108864), (float4*)d_out);
    }
  } else {
    float* out = (float*)d_out;
    k_proj<<<dim3(128, 8), 256, 0, stream>>>(ems, w_weight, w_bias, out);
    k_scores<<<dim3(B_ * (E_ / 16)), 256, 0, stream>>>(words, mask, out);
    k_ctx<<<dim3(B_ * (E_ / 16)), 256, 0, stream>>>(words, out);
  }
}

// Round 18
// 341.758 us; speedup vs baseline: 1.1479x; 1.1479x over previous
//
#include <hip/hip_runtime.h>
#include <hip/hip_bf16.h>
#include <hip/hip_fp16.h>
#include <stdint.h>

#define B_  32
#define E_  512
#define WN  2048
#define D_  1024

typedef __attribute__((ext_vector_type(8))) short short8;
typedef __attribute__((ext_vector_type(8))) _Float16 half8;
typedef __attribute__((ext_vector_type(4))) float f32x4;

__device__ int g_mask_is_int;   // 1 if mask buffer is int32 per element, 0 if uint8

__device__ __forceinline__ unsigned short f2bf(float f) {
  unsigned int u = __float_as_uint(f);
  u += 0x7fffu + ((u >> 16) & 1u);   // round-to-nearest-even
  return (unsigned short)(u >> 16);
}
__device__ __forceinline__ float bf2f(unsigned short s) {
  return __uint_as_float(((unsigned int)s) << 16);
}
__device__ __forceinline__ unsigned short f2h(float f) {
  return __half_as_ushort(__float2half(f));   // RTNE f32->f16
}
__device__ __forceinline__ float h2f(unsigned short s) {
  return __half2float(__ushort_as_half(s));
}
__device__ __forceinline__ float ftanh(float x) {
  float e = __expf(2.0f * x);
  return 1.0f - 2.0f / (e + 1.0f);
}
// XOR-swizzled byte offset within a [rows][128B] LDS plane
__device__ __forceinline__ int swz(int row, int kb) {
  return row * 128 + (kb ^ ((row & 7) << 4));
}
// 64B-row swizzle: F(X) = X ^ ((X>>6 & 7) << 4)
__device__ __forceinline__ int swz64x(int row, int kb) {
  const int X = row * 64 + kb;
  return X ^ (((X >> 6) & 7) << 4);
}
__device__ __forceinline__ uint4 pack8(unsigned short a0, unsigned short a1,
                                       unsigned short a2, unsigned short a3,
                                       unsigned short a4, unsigned short a5,
                                       unsigned short a6, unsigned short a7) {
  uint4 v;
  v.x = (unsigned int)a0 | ((unsigned int)a1 << 16);
  v.y = (unsigned int)a2 | ((unsigned int)a3 << 16);
  v.z = (unsigned int)a4 | ((unsigned int)a5 << 16);
  v.w = (unsigned int)a6 | ((unsigned int)a7 << 16);
  return v;
}
// async global->LDS, 16B per lane; LDS dst is wave-uniform base (+lane*16 HW)
__device__ __forceinline__ void gload_lds16(const void* g, void* l) {
  __builtin_amdgcn_global_load_lds(
      (const __attribute__((address_space(1))) unsigned int*)g,
      (__attribute__((address_space(3))) unsigned int*)l, 16, 0, 0);
}

// ---------------------------------------------------------------------------
// K0: detect mask dtype. int32 0/1 data => bytes at offset %4 != 0 are all 0.
// ---------------------------------------------------------------------------
__global__ void k_detect(const unsigned char* __restrict__ m) {
  if (threadIdx.x == 0) {
    int nz = 0;
    for (int i = 0; i < 1024; ++i)
      if ((i & 3) && m[i]) nz++;
    g_mask_is_int = (nz == 0) ? 1 : 0;
  }
}

// ===========================================================================
// FAST PATH (round-16 verified configuration, 343.8 us)
// ===========================================================================

// ---------------------------------------------------------------------------
// k_split_h: src f32 -> ONE f16 blob in proj's swizzled LDS-image layout.
// (verified round 15)
// ---------------------------------------------------------------------------
__global__ __launch_bounds__(256) void k_split_h(const float* __restrict__ src,
                                                 unsigned short* __restrict__ out) {
#pragma unroll
  for (int j = 0; j < 4; ++j) {
    const size_t Lg = ((size_t)blockIdx.x * 1024 + j * 256 + threadIdx.x) * 16;
    const int Lloc = (int)(Lg & 16383);
    const int TS = (int)(Lg >> 14);
    const int T = TS >> 4, s = TS & 15;
    const int row = Lloc >> 7;
    const int kb = (Lloc & 127) ^ ((row & 7) << 4);
    const int kk = kb >> 1;
    const float* sp = src + ((size_t)(T * 128 + row)) * 1024 + s * 64 + kk;
    const f32x4 v0 = *(const f32x4*)(sp);
    const f32x4 v1 = *(const f32x4*)(sp + 4);
    *(uint4*)((char*)out + Lg) =
        pack8(f2h(v0[0]), f2h(v0[1]), f2h(v0[2]), f2h(v0[3]),
              f2h(v1[0]), f2h(v1[1]), f2h(v1[2]), f2h(v1[3]));
  }
}

// ---------------------------------------------------------------------------
// k_proj_dma: proj = tanh(ems @ W^T + bias) via single f16 MFMA.
// (verified round 15)
// ---------------------------------------------------------------------------
__global__ __launch_bounds__(512) void k_proj_dma(
    const unsigned short* __restrict__ eF, const unsigned short* __restrict__ wF,
    const float* __restrict__ bias,
    unsigned short* __restrict__ outF) {
  __shared__ uint4 lds4[4096];   // 64KB
  char* pA_c = (char*)lds4;
  char* pB_c = (char*)lds4 + 16384;
  char* pA_n = (char*)lds4 + 32768;
  char* pB_n = (char*)lds4 + 49152;

  const int g = blockIdx.x;
  const int xcd = g & 7;
  const int slot = g >> 3;               // 0..127
  const int Tm = xcd + 8 * (slot >> 3);  // 0..127, pinned to XCD
  const int Tn = slot & 7;               // 0..7
  const int t = threadIdx.x, l = t & 63, wv = t >> 6;
  const int wm2 = wv >> 1;   // 0..3 -> rows wm2*32
  const int wn2 = wv & 1;    // 0..1 -> cols wn2*64

  f32x4 acc[2][4];
#pragma unroll
  for (int i = 0; i < 2; ++i)
#pragma unroll
    for (int j = 0; j < 4; ++j) acc[i][j] = (f32x4){0.f, 0.f, 0.f, 0.f};

  auto dma_stage = [&](int s, char* pA, char* pB) {
#pragma unroll
    for (int j = 0; j < 2; ++j) {
      const size_t ga = (size_t)Tm * 262144 + (size_t)s * 16384 + j * 8192 +
                        wv * 1024 + l * 16;
      gload_lds16((const char*)eF + ga, pA + j * 8192 + wv * 1024);
      const size_t gb = (size_t)Tn * 262144 + (size_t)s * 16384 + j * 8192 +
                        wv * 1024 + l * 16;
      gload_lds16((const char*)wF + gb, pB + j * 8192 + wv * 1024);
    }
  };

  auto compute_stage = [&](const char* pA, const char* pB) {
#pragma unroll
    for (int ks = 0; ks < 2; ++ks) {
      const int kb = ks * 64 + (l >> 4) * 16;
      half8 a[2], bf[4];
#pragma unroll
      for (int f = 0; f < 2; ++f)
        a[f] = *(const half8*)(pA + swz(wm2 * 32 + f * 16 + (l & 15), kb));
#pragma unroll
      for (int f = 0; f < 4; ++f)
        bf[f] = *(const half8*)(pB + swz(wn2 * 64 + f * 16 + (l & 15), kb));
#pragma unroll
      for (int fm = 0; fm < 2; ++fm)
#pragma unroll
        for (int fn = 0; fn < 4; ++fn)
          acc[fm][fn] = __builtin_amdgcn_mfma_f32_16x16x32_f16(a[fm], bf[fn], acc[fm][fn], 0, 0, 0);
    }
  };

  dma_stage(0, pA_c, pB_c);
  __syncthreads();
  for (int s = 0; s < 16; ++s) {
    if (s < 15) dma_stage(s + 1, pA_n, pB_n);
    compute_stage(pA_c, pB_c);
    __syncthreads();
    char* x;
    x = pA_c; pA_c = pA_n; pA_n = x;
    x = pB_c; pB_c = pB_n; pB_n = x;
  }

  float bcol[4];
#pragma unroll
  for (int fn = 0; fn < 4; ++fn)
    bcol[fn] = bias[Tn * 128 + wn2 * 64 + fn * 16 + (l & 15)];
#pragma unroll
  for (int fm = 0; fm < 2; ++fm)
#pragma unroll
    for (int fn = 0; fn < 4; ++fn)
#pragma unroll
      for (int q = 0; q < 4; ++q)
        acc[fm][fn][q] = ftanh(acc[fm][fn][q] + bcol[fn]);

  // epilogue: LDS transpose (f16 bits) then 32-k-stage blob store (one plane)
  unsigned short* ldsT = (unsigned short*)lds4;  // [128][136] = 34KB < 64KB
  __syncthreads();
#pragma unroll
  for (int fm = 0; fm < 2; ++fm)
#pragma unroll
    for (int fn = 0; fn < 4; ++fn)
#pragma unroll
      for (int q = 0; q < 4; ++q) {
        const int rl = wm2 * 32 + fm * 16 + (l >> 4) * 4 + q;
        const int cl = wn2 * 64 + fn * 16 + (l & 15);
        ldsT[rl * 136 + cl] = f2h(acc[fm][fn][q]);
      }
  __syncthreads();
#pragma unroll
  for (int sb = 0; sb < 4; ++sb) {
    const int L = t * 16;
    const int x6 = ((L >> 6) ^ (L >> 8)) & 1;
    const int x5 = ((L >> 5) ^ (L >> 7)) & 1;
    const int x4 = ((L >> 4) ^ (L >> 6) ^ (L >> 8)) & 1;
    const int X = (L & ~0x70) | (x6 << 6) | (x5 << 5) | (x4 << 4);
    const int row = X >> 6;
    const int cl = sb * 32 + ((X & 63) >> 1);
    uint4 v = *(const uint4*)(ldsT + row * 136 + cl);
    *(uint4*)((char*)outF + (size_t)Tm * 262144 +
              (size_t)(Tn * 4 + sb) * 8192 + L) = v;
  }
}

// ---------------------------------------------------------------------------
// k_scores_mfma: single f16 MFMA, f16 score store (verified rounds 14-16).
// ---------------------------------------------------------------------------
__global__ __launch_bounds__(512) void k_scores_mfma(
    const unsigned short* __restrict__ pF,
    const float* __restrict__ words, unsigned short* __restrict__ sc) {
  __shared__ uint4 lds4[5120];  // 80KB
  char* pA_c = (char*)lds4;              // 32KB: [4 tiles][8KB swz64x]
  char* pA_n = (char*)lds4 + 32768;
  char* pB_c = (char*)lds4 + 65536;      // 8KB: [128 n][64B swz64x]
  char* pB_n = (char*)lds4 + 73728;

  const int g = blockIdx.x;
  const int b = (g & 7) + 8 * (g >> 7);   // XCD-pinned batch (bijective)
  const int n0 = ((g >> 3) & 15) * 128;

  const int t = threadIdx.x, l = t & 63, wv = t >> 6;
  const int wm4 = wv >> 1;    // 0..3 -> m tile (128 rows each)
  const int wn2 = wv & 1;     // 0..1 -> n base local = wn2*64

  f32x4 acc[8][4];
#pragma unroll
  for (int i = 0; i < 8; ++i)
#pragma unroll
    for (int j = 0; j < 4; ++j) acc[i][j] = (f32x4){0.f, 0.f, 0.f, 0.f};

  f32x4 br0, br1;
  const int bn = t >> 2;          // B n-row 0..127
  const int bc = (t & 3) * 8;     // f32 col base within 32

  auto dma_A = [&](int s, char* pA) {
#pragma unroll
    for (int j = 0; j < 4; ++j) {
      const size_t gb = (size_t)(b * 4 + j) * 262144 + (size_t)s * 8192 +
                        wv * 1024 + l * 16;
      gload_lds16((const char*)pF + gb, pA + j * 8192 + wv * 1024);
    }
  };

  auto load_B = [&](int s) {
    const float* bs = words + (size_t)b * WN * D_ + (size_t)(n0 + bn) * 1024 +
                      s * 32 + bc;
    br0 = *(const f32x4*)(bs);
    br1 = *(const f32x4*)(bs + 4);
  };

  auto write_B = [&](char* pB) {
    unsigned short hB[8];
#pragma unroll
    for (int j = 0; j < 4; ++j) {
      hB[j] = f2h(br0[j]);
      hB[4 + j] = f2h(br1[j]);
    }
    const int o = swz64x(bn, (t & 3) * 16);
    *(uint4*)(pB + o) = pack8(hB[0], hB[1], hB[2], hB[3], hB[4], hB[5], hB[6], hB[7]);
  };

  auto compute_stage = [&](const char* pA, const char* pB) {
    const int kb0 = (l >> 4) * 16;
    half8 bf[4];
#pragma unroll
    for (int f = 0; f < 4; ++f) {
      const int n = wn2 * 64 + f * 16 + (l & 15);
      bf[f] = *(const half8*)(pB + swz64x(n, kb0));
    }
#pragma unroll
    for (int fm = 0; fm < 8; ++fm) {
      const int row = fm * 16 + (l & 15);
      const half8 a = *(const half8*)(pA + wm4 * 8192 + swz64x(row, kb0));
#pragma unroll
      for (int fn = 0; fn < 4; ++fn)
        acc[fm][fn] = __builtin_amdgcn_mfma_f32_16x16x32_f16(a, bf[fn], acc[fm][fn], 0, 0, 0);
    }
  };

  // prologue
  load_B(0);
  dma_A(0, pA_c);
  write_B(pB_c);
  __syncthreads();

  for (int s = 0; s < 32; ++s) {
    if (s < 31) {
      load_B(s + 1);
      dma_A(s + 1, pA_n);
    }
    compute_stage(pA_c, pB_c);
    if (s < 31) write_B(pB_n);
    __syncthreads();  // drains DMA (vmcnt) + ds_writes (lgkm)
    char* x;
    x = pA_c; pA_c = pA_n; pA_n = x;
    x = pB_c; pB_c = pB_n; pB_n = x;
  }

  // store f16 scores
#pragma unroll
  for (int fm = 0; fm < 8; ++fm)
#pragma unroll
    for (int fn = 0; fn < 4; ++fn)
#pragma unroll
      for (int q = 0; q < 4; ++q) {
        const int row = wm4 * 128 + fm * 16 + (l >> 4) * 4 + q;
        const int col = n0 + wn2 * 64 + fn * 16 + (l & 15);
        sc[((size_t)b * 512 + row) * 2048 + col] = f2h(acc[fm][fn][q]);
      }
}

// ---------------------------------------------------------------------------
// k_softmax: reads f16 scores, writes f16 att blob (64-stage layout for
// round-16 k_pv: slot = ee*128 + (((t&7)*16) ^ ((ee&7)<<4))). Verified r16.
// ---------------------------------------------------------------------------
__global__ __launch_bounds__(256) void k_softmax(const unsigned short* __restrict__ sc,
                                                 const void* __restrict__ mask,
                                                 unsigned short* __restrict__ blob) {
  __shared__ float red[8];
  const int row = blockIdx.x;
  const int t = threadIdx.x;
  const int wave = t >> 6;
  const unsigned short* rp = sc + (size_t)row * 2048;
  float v[8];
  {
    const half8 hv = *(const half8*)(rp + t * 8);
#pragma unroll
    for (int i = 0; i < 8; ++i) v[i] = (float)hv[i];
  }
  if (g_mask_is_int) {
    const int* mp = (const int*)mask + (size_t)row * 2048 + t * 8;
    const int4 m0 = *(const int4*)mp;
    const int4 m1 = *(const int4*)(mp + 4);
    if (m0.x) v[0] = -INFINITY;
    if (m0.y) v[1] = -INFINITY;
    if (m0.z) v[2] = -INFINITY;
    if (m0.w) v[3] = -INFINITY;
    if (m1.x) v[4] = -INFINITY;
    if (m1.y) v[5] = -INFINITY;
    if (m1.z) v[6] = -INFINITY;
    if (m1.w) v[7] = -INFINITY;
  } else {
    const unsigned char* mp = (const unsigned char*)mask + (size_t)row * 2048 + t * 8;
    const uchar4 m0 = *(const uchar4*)mp;
    const uchar4 m1 = *(const uchar4*)(mp + 4);
    if (m0.x) v[0] = -INFINITY;
    if (m0.y) v[1] = -INFINITY;
    if (m0.z) v[2] = -INFINITY;
    if (m0.w) v[3] = -INFINITY;
    if (m1.x) v[4] = -INFINITY;
    if (m1.y) v[5] = -INFINITY;
    if (m1.z) v[6] = -INFINITY;
    if (m1.w) v[7] = -INFINITY;
  }
  float mx = v[0];
#pragma unroll
  for (int i = 1; i < 8; ++i) mx = fmaxf(mx, v[i]);
#pragma unroll
  for (int off = 32; off > 0; off >>= 1) mx = fmaxf(mx, __shfl_xor(mx, off));
  if ((t & 63) == 0) red[wave] = mx;
  __syncthreads();
  mx = fmaxf(fmaxf(red[0], red[1]), fmaxf(red[2], red[3]));
  float e[8];
  float sum = 0.0f;
#pragma unroll
  for (int i = 0; i < 8; ++i) {
    e[i] = __expf(v[i] - mx);
    sum += e[i];
  }
#pragma unroll
  for (int off = 32; off > 0; off >>= 1) sum += __shfl_xor(sum, off);
  if ((t & 63) == 0) red[4 + wave] = sum;
  __syncthreads();
  const float tot = (red[4] + red[5]) + (red[6] + red[7]);
  const float rinv = 1.0f / tot;

  const int b = row >> 9, ee = row & 511;
  const uint4 pk = pack8(f2h(e[0] * rinv), f2h(e[1] * rinv),
                         f2h(e[2] * rinv), f2h(e[3] * rinv),
                         f2h(e[4] * rinv), f2h(e[5] * rinv),
                         f2h(e[6] * rinv), f2h(e[7] * rinv));
  char* dst = (char*)blob + (size_t)b * 2097152 + (size_t)(t >> 3) * 65536 +
              ee * 128 + (((t & 7) * 16) ^ ((ee & 7) << 4));
  *(uint4*)dst = pk;
}

// ---------------------------------------------------------------------------
// k_pv: ctx = att @ words, f16 MFMA (verified round 16).
// ---------------------------------------------------------------------------
__global__ __launch_bounds__(512) void k_pv(
    const unsigned short* __restrict__ blob, const float* __restrict__ words,
    float* __restrict__ ctx) {
  __shared__ uint4 lds4[10240];           // 160KB
  char* pAc = (char*)lds4;
  char* pAn = (char*)lds4 + 65536;
  char* pBc = (char*)lds4 + 131072;
  char* pBn = (char*)lds4 + 147456;

  const int g = blockIdx.x;
  const int b = (g & 7) + 8 * (g >> 6);   // XCD-pinned batch
  const int wt = (g >> 3) & 7;
  const int w0 = wt * 128;

  const int t = threadIdx.x, l = t & 63, wv = t >> 6;
  const int wm4 = wv >> 1;
  const int wn2 = wv & 1;

  const char* blobB = (const char*)blob + (size_t)b * 2097152;

  f32x4 acc[8][4];
#pragma unroll
  for (int i = 0; i < 8; ++i)
#pragma unroll
    for (int j = 0; j < 4; ++j) acc[i][j] = (f32x4){0.f, 0.f, 0.f, 0.f};

  f32x4 bv0a, bv0b, bv1a, bv1b;
  const int np2 = (t & 31) * 2;
  const int wc = (t >> 5) * 8;

  auto dma_A = [&](int s, char* pA) {
    const char* gp = blobB + (size_t)s * 65536 + wv * 8192 + l * 16;
#pragma unroll
    for (int j = 0; j < 8; ++j)
      gload_lds16(gp + j * 1024, pA + wv * 8192 + j * 1024);
  };

  auto load_B = [&](int s) {
    const float* wp = words + (size_t)b * WN * D_ +
                      (size_t)(s * 64 + np2) * 1024 + w0 + wc;
    bv0a = *(const f32x4*)(wp);
    bv0b = *(const f32x4*)(wp + 4);
    bv1a = *(const f32x4*)(wp + 1024);
    bv1b = *(const f32x4*)(wp + 1028);
  };

  auto write_B = [&](char* pB) {
#pragma unroll
    for (int i = 0; i < 8; ++i) {
      const int w = wc + i;
      const float x0 = (i < 4) ? bv0a[i & 3] : bv0b[i & 3];
      const float x1 = (i < 4) ? bv1a[i & 3] : bv1b[i & 3];
      const unsigned int pk =
          (unsigned int)f2h(x0) | ((unsigned int)f2h(x1) << 16);
      *(unsigned int*)(pB + w * 128 + ((np2 * 2) ^ ((w & 7) << 4))) = pk;
    }
  };

  auto compute_stage = [&](const char* pA, const char* pB) {
#pragma unroll
    for (int ks = 0; ks < 2; ++ks) {
      half8 a[8];
      const int kb = ks * 64 + (l >> 4) * 16;
#pragma unroll
      for (int f = 0; f < 8; ++f) {
        const int row = wm4 * 128 + f * 16 + (l & 15);
        a[f] = *(const half8*)(pA + swz(row, kb));
      }
      half8 bb[4];
#pragma unroll
      for (int f = 0; f < 4; ++f) {
        const int row = wn2 * 64 + f * 16 + (l & 15);
        bb[f] = *(const half8*)(pB + swz(row, kb));
      }
#pragma unroll
      for (int fm = 0; fm < 8; ++fm)
#pragma unroll
        for (int fn = 0; fn < 4; ++fn)
          acc[fm][fn] = __builtin_amdgcn_mfma_f32_16x16x32_f16(a[fm], bb[fn], acc[fm][fn], 0, 0, 0);
    }
  };

  load_B(0);
  dma_A(0, pAc);
  write_B(pBc);
  __syncthreads();

  for (int s = 0; s < 32; ++s) {
    if (s < 31) {
      load_B(s + 1);
      dma_A(s + 1, pAn);
    }
    compute_stage(pAc, pBc);
    if (s < 31) write_B(pBn);
    __syncthreads();
    char* t1 = pAc; pAc = pAn; pAn = t1;
    char* t2 = pBc; pBc = pBn; pBn = t2;
  }

#pragma unroll
  for (int fm = 0; fm < 8; ++fm)
#pragma unroll
    for (int fn = 0; fn < 4; ++fn)
#pragma unroll
      for (int q = 0; q < 4; ++q) {
        const int row = wm4 * 128 + fm * 16 + (l >> 4) * 4 + q;
        const int col = w0 + wn2 * 64 + fn * 16 + (l & 15);
        ctx[((size_t)b * 512 + row) * 1024 + col] = acc[fm][fn][q];
      }
}

// ---------------------------------------------------------------------------
// k_copy: ctx (ws) -> d_out, float4 grid-stride. (small-ws fallback only)
// ---------------------------------------------------------------------------
__global__ __launch_bounds__(256) void k_copy(const float4* __restrict__ src,
                                              float4* __restrict__ dst) {
  const int n4 = 16384 * 1024 / 4;
  int i = blockIdx.x * 256 + threadIdx.x;
  const int stride = gridDim.x * 256;
  for (; i < n4; i += stride) dst[i] = src[i];
}

// ===========================================================================
// FALLBACK PATH (round-2 verified kernels; used if ws too small)
// ===========================================================================
__global__ __launch_bounds__(256, 4) void k_proj(const float* __restrict__ A,
                                                 const float* __restrict__ W,
                                                 const float* __restrict__ bias,
                                                 float* __restrict__ out) {
  __shared__ float As[32][132];
  __shared__ float Bs[32][132];
  const int t = threadIdx.x;
  const int m0 = blockIdx.x * 128;
  const int n0 = blockIdx.y * 128;
  const int tm = t >> 4;
  const int tn = t & 15;
  const int lrow = t >> 1;
  const int lk = (t & 1) * 16;

  float acc[8][8];
#pragma unroll
  for (int i = 0; i < 8; ++i)
#pragma unroll
    for (int j = 0; j < 8; ++j) acc[i][j] = 0.0f;

  const float* Arow = A + (size_t)(m0 + lrow) * D_ + lk;
  const float* Wrow = W + (size_t)(n0 + lrow) * D_ + lk;

  for (int k0 = 0; k0 < D_; k0 += 32) {
    __syncthreads();
#pragma unroll
    for (int j = 0; j < 4; ++j) {
      const float4 va = *(const float4*)(Arow + k0 + j * 4);
      As[lk + j * 4 + 0][lrow] = va.x;
      As[lk + j * 4 + 1][lrow] = va.y;
      As[lk + j * 4 + 2][lrow] = va.z;
      As[lk + j * 4 + 3][lrow] = va.w;
      const float4 vb = *(const float4*)(Wrow + k0 + j * 4);
      Bs[lk + j * 4 + 0][lrow] = vb.x;
      Bs[lk + j * 4 + 1][lrow] = vb.y;
      Bs[lk + j * 4 + 2][lrow] = vb.z;
      Bs[lk + j * 4 + 3][lrow] = vb.w;
    }
    __syncthreads();
#pragma unroll 8
    for (int k = 0; k < 32; ++k) {
      float a[8], bb[8];
      *(float4*)(a + 0) = *(const float4*)&As[k][tm * 4];
      *(float4*)(a + 4) = *(const float4*)&As[k][tm * 4 + 64];
      *(float4*)(bb + 0) = *(const float4*)&Bs[k][tn * 4];
      *(float4*)(bb + 4) = *(const float4*)&Bs[k][tn * 4 + 64];
#pragma unroll
      for (int i = 0; i < 8; ++i)
#pragma unroll
        for (int j = 0; j < 8; ++j) acc[i][j] = fmaf(a[i], bb[j], acc[i][j]);
    }
  }

  float bn[8];
#pragma unroll
  for (int j = 0; j < 8; ++j) bn[j] = bias[n0 + tn * 4 + (j & 3) + (j >> 2) * 64];
#pragma unroll
  for (int i = 0; i < 8; ++i) {
    const int m = m0 + tm * 4 + (i & 3) + (i >> 2) * 64;
    float4 v0, v1;
    v0.x = tanhf(acc[i][0] + bn[0]);
    v0.y = tanhf(acc[i][1] + bn[1]);
    v0.z = tanhf(acc[i][2] + bn[2]);
    v0.w = tanhf(acc[i][3] + bn[3]);
    v1.x = tanhf(acc[i][4] + bn[4]);
    v1.y = tanhf(acc[i][5] + bn[5]);
    v1.z = tanhf(acc[i][6] + bn[6]);
    v1.w = tanhf(acc[i][7] + bn[7]);
    *(float4*)(out + (size_t)m * D_ + n0 + tn * 4) = v0;
    *(float4*)(out + (size_t)m * D_ + n0 + tn * 4 + 64) = v1;
  }
}

__global__ __launch_bounds__(256) void k_scores(const float* __restrict__ words,
                                                const void* __restrict__ mask,
                                                float* __restrict__ pa) {
  __shared__ float Pt[1024][18];
  __shared__ float Ws[64][268];
  const int t = threadIdx.x;
  const int b = blockIdx.x >> 5;
  const int et = blockIdx.x & 31;
  const int e0 = et * 16;
  const int eg = t >> 5;
  const int ng = t & 31;
  const int mask_is_int = g_mask_is_int;
  const float* wbase = words + (size_t)b * WN * D_;

  {
    const int row = t >> 4;
    const int dj = (t & 15) * 4;
    const float* pr = pa + (size_t)(b * E_ + e0 + row) * D_;
#pragma unroll
    for (int rr = 0; rr < 16; ++rr) {
      const float4 v = *(const float4*)(pr + dj + rr * 64);
      Pt[dj + rr * 64 + 0][row] = v.x;
      Pt[dj + rr * 64 + 1][row] = v.y;
      Pt[dj + rr * 64 + 2][row] = v.z;
      Pt[dj + rr * 64 + 3][row] = v.w;
    }
  }

  float s[2][64];
#pragma unroll
  for (int i = 0; i < 2; ++i)
#pragma unroll
    for (int u = 0; u < 64; ++u) s[i][u] = 0.0f;

  const int nl = t >> 3;
  const int d4 = (t & 7) * 4;

  for (int dk = 0; dk < D_; dk += 64) {
#pragma unroll
    for (int nb = 0; nb < 8; ++nb) {
      __syncthreads();
#pragma unroll
      for (int rr = 0; rr < 8; ++rr) {
#pragma unroll
        for (int hh = 0; hh < 2; ++hh) {
          const int n = nl + rr * 32;
          const int d = d4 + hh * 32;
          const float4 v = *(const float4*)(wbase + (size_t)(nb * 256 + n) * D_ + dk + d);
          Ws[d + 0][n] = v.x;
          Ws[d + 1][n] = v.y;
          Ws[d + 2][n] = v.z;
          Ws[d + 3][n] = v.w;
        }
      }
      __syncthreads();
#pragma unroll 2
      for (int k = 0; k < 64; ++k) {
        const float2 a = *(const float2*)&Pt[dk + k][eg * 2];
        const float4 b0 = *(const float4*)&Ws[k][ng * 4];
        const float4 b1 = *(const float4*)&Ws[k][128 + ng * 4];
        const float aa[2] = {a.x, a.y};
        const float bb[8] = {b0.x, b0.y, b0.z, b0.w, b1.x, b1.y, b1.z, b1.w};
#pragma unroll
        for (int i = 0; i < 2; ++i)
#pragma unroll
          for (int u = 0; u < 8; ++u)
            s[i][nb * 8 + u] = fmaf(aa[i], bb[u], s[i][nb * 8 + u]);
      }
    }
  }

#pragma unroll
  for (int i = 0; i < 2; ++i) {
    const int e = e0 + eg * 2 + i;
#pragma unroll
    for (int nb = 0; nb < 8; ++nb)
#pragma unroll
      for (int q = 0; q < 2; ++q) {
        const size_t moff = (size_t)(b * E_ + e) * WN + nb * 256 + q * 128 + ng * 4;
        int mx, my, mz, mw;
        if (mask_is_int) {
          const int4 mv = *(const int4*)((const int*)mask + moff);
          mx = mv.x; my = mv.y; mz = mv.z; mw = mv.w;
        } else {
          const uchar4 mv = *(const uchar4*)((const unsigned char*)mask + moff);
          mx = mv.x; my = mv.y; mz = mv.z; mw = mv.w;
        }
        if (mx) s[i][nb * 8 + q * 4 + 0] = -1e30f;
        if (my) s[i][nb * 8 + q * 4 + 1] = -1e30f;
        if (mz) s[i][nb * 8 + q * 4 + 2] = -1e30f;
        if (mw) s[i][nb * 8 + q * 4 + 3] = -1e30f;
      }
    float m = -1e30f;
#pragma unroll
    for (int u = 0; u < 64; ++u) m = fmaxf(m, s[i][u]);
#pragma unroll
    for (int off = 16; off > 0; off >>= 1) m = fmaxf(m, __shfl_xor(m, off));
    float sum = 0.0f;
#pragma unroll
    for (int u = 0; u < 64; ++u) {
      const float p = __expf(s[i][u] - m);
      s[i][u] = p;
      sum += p;
    }
#pragma unroll
    for (int off = 16; off > 0; off >>= 1) sum += __shfl_xor(sum, off);
    const float rinv = 1.0f / sum;

    unsigned short* ar2 = (unsigned short*)(pa + (size_t)(b * E_ + e) * WN / 2);
#pragma unroll
    for (int nb = 0; nb < 8; ++nb)
#pragma unroll
      for (int q = 0; q < 2; ++q) {
        ushort4 pk;
        pk.x = f2bf(s[i][nb * 8 + q * 4 + 0] * rinv);
        pk.y = f2bf(s[i][nb * 8 + q * 4 + 1] * rinv);
        pk.z = f2bf(s[i][nb * 8 + q * 4 + 2] * rinv);
        pk.w = f2bf(s[i][nb * 8 + q * 4 + 3] * rinv);
        *(ushort4*)(ar2 + nb * 256 + q * 128 + ng * 4) = pk;
      }
  }
}

__global__ __launch_bounds__(256) void k_ctx(const float* __restrict__ words,
                                             float* __restrict__ pa) {
  __shared__ unsigned short att_s[16][2048];
  __shared__ unsigned short Wb[256][132];
  const int t = threadIdx.x;
  const int b = blockIdx.x >> 5;
  const int et = blockIdx.x & 31;
  const int e0 = et * 16;
  const int eg = t >> 5;
  const int wg = t & 31;
  const float* wbase = words + (size_t)b * WN * D_;

  {
    const int row = t >> 4;
    const int cj = t & 15;
    const uint4* pr = (const uint4*)(pa + (size_t)(b * E_ + e0 + row) * D_);
#pragma unroll
    for (int rr = 0; rr < 16; ++rr) {
      const int c = cj + rr * 16;
      const uint4 v = pr[c];
      *(uint4*)&att_s[row][c * 8] = v;
    }
  }

  float acc[2][32];
#pragma unroll
  for (int i = 0; i < 2; ++i)
#pragma unroll
    for (int u = 0; u < 32; ++u) acc[i][u] = 0.0f;

  const int nlg = t >> 5;
  const int w4 = (t & 31) * 4;

  for (int nb = 0; nb < 8; ++nb) {
#pragma unroll
    for (int q = 0; q < 8; ++q) {
      __syncthreads();
#pragma unroll
      for (int rr = 0; rr < 32; ++rr) {
        const int n = nlg + rr * 8;
        const float4 v = *(const float4*)(wbase + (size_t)(nb * 256 + n) * D_ + q * 128 + w4);
        ushort4 pk;
        pk.x = f2bf(v.x);
        pk.y = f2bf(v.y);
        pk.z = f2bf(v.z);
        pk.w = f2bf(v.w);
        *(ushort4*)&Wb[n][w4] = pk;
      }
      __syncthreads();
#pragma unroll 4
      for (int n2 = 0; n2 < 128; ++n2) {
        const int n = n2 * 2;
        const ushort4 r0 = *(const ushort4*)&Wb[n][wg * 4];
        const ushort4 r1 = *(const ushort4*)&Wb[n + 1][wg * 4];
        const float w0[4] = {bf2f(r0.x), bf2f(r0.y), bf2f(r0.z), bf2f(r0.w)};
        const float w1[4] = {bf2f(r1.x), bf2f(r1.y), bf2f(r1.z), bf2f(r1.w)};
#pragma unroll
        for (int i = 0; i < 2; ++i) {
          const unsigned int aw = *(const unsigned int*)&att_s[eg * 2 + i][nb * 256 + n];
          const float a0 = bf2f((unsigned short)(aw & 0xffffu));
          const float a1 = bf2f((unsigned short)(aw >> 16));
#pragma unroll
          for (int j = 0; j < 4; ++j)
            acc[i][q * 4 + j] = fmaf(a0, w0[j], fmaf(a1, w1[j], acc[i][q * 4 + j]));
        }
      }
    }
  }

#pragma unroll
  for (int i = 0; i < 2; ++i) {
    float* orow = pa + (size_t)(b * E_ + e0 + eg * 2 + i) * D_;
#pragma unroll
    for (int q = 0; q < 8; ++q) {
      float4 v;
      v.x = acc[i][q * 4 + 0];
      v.y = acc[i][q * 4 + 1];
      v.z = acc[i][q * 4 + 2];
      v.w = acc[i][q * 4 + 3];
      *(float4*)(orow + q * 128 + wg * 4) = v;
    }
  }
}

extern "C" void kernel_launch(void* const* d_in, const int* in_sizes, int n_in,
                              void* d_out, int out_size, void* d_ws, size_t ws_size,
                              hipStream_t stream) {
  const float* ems = (const float*)d_in[0];
  const float* words = (const float*)d_in[1];
  const void* mask = d_in[2];
  const float* w_weight = (const float*)d_in[3];
  const float* w_bias = (const float*)d_in[4];

  k_detect<<<1, 64, 0, stream>>>((const unsigned char*)mask);

  const size_t ws_need = (size_t)16384 * 2048 * 4;          // 128 MB budget
  const size_t ws_big = ws_need + (size_t)32 * 2097152;     // +64 MB blob
  if (ws_size >= ws_need) {
    unsigned short* pF = (unsigned short*)d_out;    // 32MB f16 proj blob
    unsigned short* scH = (unsigned short*)d_ws;    // 64MB f16 scores
    unsigned short* eF = (unsigned short*)((char*)d_ws + (size_t)67108864);  // 32MB
    unsigned short* wF = eF + (size_t)16384 * 1024;                          // 2MB
    // 0. convert ems (128 tiles) and W (8 tiles) into f16 swizzled blobs
    k_split_h<<<dim3(2048), 256, 0, stream>>>(ems, eF);
    k_split_h<<<dim3(128), 256, 0, stream>>>(w_weight, wF);
    // 1. proj (single f16 MFMA, XCD-pinned, 64KB LDS) -> f16 blob in d_out
    k_proj_dma<<<dim3(1024), 512, 0, stream>>>(eF, wF, w_bias, pF);
    // 2. scores (single f16 MFMA) -> f16 scores in ws[0..64MB)
    k_scores_mfma<<<dim3(512), 512, 0, stream>>>(pF, words, scH);
    if (ws_size >= ws_big) {
      // big-ws path: att blob in ws; ctx -> d_out direct
      unsigned short* blob = (unsigned short*)((char*)d_ws + ws_need);
      k_softmax<<<dim3(16384), 256, 0, stream>>>(scH, mask, blob);
      k_pv<<<dim3(256), 512, 0, stream>>>(blob, words, (float*)d_out);
    } else {
      // small-ws path: blob in d_out (proj blob dead), ctx -> ws+64MB, copy
      k_softmax<<<dim3(16384), 256, 0, stream>>>(scH, mask, (unsigned short*)d_out);
      k_pv<<<dim3(256), 512, 0, stream>>>((const unsigned short*)d_out, words,
                                          (float*)((char*)d_ws + 67108864));
      k_copy<<<dim3(2048), 256, 0, stream>>>(
          (const float4*)((char*)d_ws + 67108864), (float4*)d_out);
    }
  } else {
    float* out = (float*)d_out;
    k_proj<<<dim3(128, 8), 256, 0, stream>>>(ems, w_weight, w_bias, out);
    k_scores<<<dim3(B_ * (E_ / 16)), 256, 0, stream>>>(words, mask, out);
    k_ctx<<<dim3(B_ * (E_ / 16)), 256, 0, stream>>>(words, out);
  }
}